// Round 7
// baseline (159.907 us; speedup 1.0000x reference)
//
#include <hip/hip_runtime.h>

using short8 = __attribute__((ext_vector_type(8))) short;
using f32x4  = __attribute__((ext_vector_type(4))) float;
using f32x16 = __attribute__((ext_vector_type(16))) float;

__device__ __forceinline__ unsigned short f2bf(float f) {
  unsigned u = __float_as_uint(f);
  u += 0x7fffu + ((u >> 16) & 1u);
  return (unsigned short)(u >> 16);
}

// ---------------- Kernel A: temporal conv over flattened (N*F_IN) axis ----------------
__global__ __launch_bounds__(256) void conv_kernel(const float* __restrict__ x,
                                                   const float* __restrict__ cw,
                                                   const float* __restrict__ cb,
                                                   unsigned short* __restrict__ xt) {
  __shared__ float tile[12][264];
  __shared__ float cws[432];
  __shared__ float cbs[12];
  const int b  = blockIdx.y;
  const int p0 = blockIdx.x << 8;
  const int tid = threadIdx.x;
  for (int i = tid; i < 432; i += 256) cws[i] = cw[i];
  if (tid < 12) cbs[tid] = cb[tid];
  for (int t = 0; t < 12; ++t) {
    for (int i = tid; i < 258; i += 256) {
      int gp = p0 + i - 1;
      float v = 0.f;
      if (gp >= 0 && gp < 2048 * 32) {
        int n = gp >> 5, f = gp & 31;
        v = x[(((size_t)b * 2048 + n) * 12 + t) * 32 + f];
      }
      tile[t][i] = v;
    }
  }
  __syncthreads();
  float acc[12];
#pragma unroll
  for (int to = 0; to < 12; ++to) acc[to] = cbs[to];
#pragma unroll
  for (int ti = 0; ti < 12; ++ti) {
    float x0 = tile[ti][tid], x1 = tile[ti][tid + 1], x2 = tile[ti][tid + 2];
#pragma unroll
    for (int to = 0; to < 12; ++to) {
      const float* wp = &cws[(to * 12 + ti) * 3];
      acc[to] += x0 * wp[0] + x1 * wp[1] + x2 * wp[2];
    }
  }
  const int p = p0 + tid, n = p >> 5, f = p & 31;
  unsigned short* op = xt + ((size_t)b * 2048 + n) * 384 + f;
#pragma unroll
  for (int to = 0; to < 12; ++to) op[to * 32] = f2bf(acc[to]);
}

// ---------------- Transpose f32 [rows][cols] -> bf16 [cols][rows] (for W) ----------------
__global__ __launch_bounds__(256) void transpose_f2b_kernel(const float* __restrict__ in,
                                                            unsigned short* __restrict__ out,
                                                            int rows, int cols) {
  __shared__ float tile[32][33];
  const int r0 = blockIdx.x * 32, c0 = blockIdx.y * 32;
  const int li = threadIdx.x >> 5, ci = threadIdx.x & 31;
#pragma unroll
  for (int p = 0; p < 4; ++p) {
    int r = li + p * 8;
    tile[r][ci] = in[(size_t)(r0 + r) * cols + c0 + ci];
  }
  __syncthreads();
#pragma unroll
  for (int p = 0; p < 4; ++p) {
    int c = li + p * 8;
    out[(size_t)(c0 + c) * rows + r0 + ci] = f2bf(tile[ci][c]);
  }
}

// ---------------- adj int32 -> bitmask [2048][64] words ----------------
__global__ __launch_bounds__(256) void adjmask_kernel(const int* __restrict__ adj,
                                                      unsigned* __restrict__ adjm) {
  const int wv = (blockIdx.x << 2) + (threadIdx.x >> 6);
  const int lane = threadIdx.x & 63;
  const int row = wv >> 5, j0 = (wv & 31) << 6;
  unsigned long long mask = __ballot(adj[(size_t)row * 2048 + j0 + lane] > 0);
  if (lane == 0) {
    adjm[row * 64 + (j0 >> 5)]     = (unsigned)mask;
    adjm[row * 64 + (j0 >> 5) + 1] = (unsigned)(mask >> 32);
  }
}

// ---------------- Kernel B: Wh = xt @ W, writes PACKED B-frag tiles + fused f1/f2 ----------------
// block: 32 rows (rb 0..255), 8 waves = 2 rg(16 rows) x 4 cg(96 cols)
// whp[b][ct 12][jc 128][lane 64][8 bf16]: lane l elem e = Wh[jc*16 + (l>>5)*8 + e][ct*32 + (l&31)]
__global__ __launch_bounds__(512) void gemm_wh2_kernel(const unsigned short* __restrict__ xt,
                                                       const unsigned short* __restrict__ Wt,
                                                       const float* __restrict__ a,
                                                       unsigned short* __restrict__ whp,
                                                       float* __restrict__ f1,
                                                       float* __restrict__ f2) {
  __shared__ unsigned short wtile[32][392];
  __shared__ float s1s[32], s2s[32];
  const int tid = threadIdx.x;
  const int rb = blockIdx.x;
  const int b = rb >> 6, jg = rb & 63;
  const int r0 = rb << 5;
  const int w = tid >> 6, lane = tid & 63;
  const int rg = w >> 2, cg = w & 3;
  const int il = lane & 15, kg = lane >> 4;
  if (tid < 32) { s1s[tid] = 0.f; s2s[tid] = 0.f; }
  __syncthreads();

  f32x4 acc[6];
#pragma unroll
  for (int t = 0; t < 6; ++t) acc[t] = (f32x4){0.f, 0.f, 0.f, 0.f};
  const unsigned short* ap = xt + (size_t)(r0 + rg * 16 + il) * 384 + kg * 8;
#pragma unroll
  for (int kk = 0; kk < 12; ++kk) {
    short8 af = *reinterpret_cast<const short8*>(ap + kk * 32);
#pragma unroll
    for (int t = 0; t < 6; ++t) {
      const int c = cg * 96 + t * 16 + il;
      short8 bf = *reinterpret_cast<const short8*>(Wt + (size_t)c * 384 + kk * 32 + kg * 8);
      acc[t] = __builtin_amdgcn_mfma_f32_16x16x32_bf16(af, bf, acc[t], 0, 0, 0);
    }
  }
  // fused f1/f2 partials
  float p1[4] = {0.f, 0.f, 0.f, 0.f}, p2[4] = {0.f, 0.f, 0.f, 0.f};
#pragma unroll
  for (int t = 0; t < 6; ++t) {
    const int c = cg * 96 + t * 16 + il;
    const float a1v = a[c], a2v = a[384 + c];
#pragma unroll
    for (int r = 0; r < 4; ++r) { p1[r] += acc[t][r] * a1v; p2[r] += acc[t][r] * a2v; }
  }
#pragma unroll
  for (int off = 1; off < 16; off <<= 1) {
#pragma unroll
    for (int r = 0; r < 4; ++r) { p1[r] += __shfl_xor(p1[r], off); p2[r] += __shfl_xor(p2[r], off); }
  }
  if (il == 0) {
#pragma unroll
    for (int r = 0; r < 4; ++r) {
      atomicAdd(&s1s[rg * 16 + kg * 4 + r], p1[r]);
      atomicAdd(&s2s[rg * 16 + kg * 4 + r], p2[r]);
    }
  }
  // dump bf16 C to LDS
#pragma unroll
  for (int t = 0; t < 6; ++t)
#pragma unroll
    for (int r = 0; r < 4; ++r)
      wtile[rg * 16 + kg * 4 + r][cg * 96 + t * 16 + il] = f2bf(acc[t][r]);
  __syncthreads();

  // write packed B-frag tiles: 24 tiles (ct 12 x jh 2) x 64 lanes
#pragma unroll
  for (int rep = 0; rep < 3; ++rep) {
    const int flat = rep * 512 + tid;
    const int tile = flat >> 6, l = flat & 63;
    const int ct = tile >> 1, jh = tile & 1;
    const int l5 = l & 31, hw2 = l >> 5;
    short8 v;
#pragma unroll
    for (int e = 0; e < 8; ++e)
      v[e] = (short)wtile[jh * 16 + hw2 * 8 + e][ct * 32 + l5];
    *reinterpret_cast<short8*>((char*)whp +
        ((((size_t)b * 12 + ct) * 128 + jg * 2 + jh) << 10) + l * 16) = v;
  }
  if (tid < 32) { f1[r0 + tid] = s1s[tid]; f2[r0 + tid] = s2s[tid]; }
}

// ---------------- per-batch max of f2 ----------------
__global__ __launch_bounds__(256) void f2max_kernel(const float* __restrict__ f2,
                                                    float* __restrict__ gmax) {
  __shared__ float wm[4];
  const int b = blockIdx.x;
  const int tid = threadIdx.x;
  float m = -3.0e38f;
  for (int i = tid; i < 2048; i += 256) m = fmaxf(m, f2[b * 2048 + i]);
#pragma unroll
  for (int off = 32; off; off >>= 1) m = fmaxf(m, __shfl_xor(m, off));
  if ((tid & 63) == 0) wm[tid >> 6] = m;
  __syncthreads();
  if (tid == 0) gmax[b] = fmaxf(fmaxf(wm[0], wm[1]), fmaxf(wm[2], wm[3]));
}

// ---------------- Kernel E: attention v6 — 96-col waves, 2-deep prefetch, 3 waves/SIMD ----------------
// grid 1024: bi = rb*16 + (b*4 + ch); 4 waves = 4 ks (512 j each, 32 steps of 16 j).
// Wave: 32 rows x 96 cols (3 tiles, acc 48 regs). No barriers until epilogue.
__global__ __launch_bounds__(256, 3) void attn6_kernel(const float* __restrict__ f1,
                                                       const float* __restrict__ f2,
                                                       const unsigned* __restrict__ adjm,
                                                       const unsigned short* __restrict__ whp,
                                                       const float* __restrict__ gmax,
                                                       float* __restrict__ out) {
  __shared__ float red[4][32][96];      // 48 KB
  __shared__ float dred[128];
  const int bi = blockIdx.x;
  const int c16 = bi & 15;
  const int b  = c16 >> 2;
  const int ch = c16 & 3;
  const int i0 = (bi >> 4) << 5;
  const int tid = threadIdx.x;
  const int ks = tid >> 6;
  const int lane = tid & 63;
  const int l5 = lane & 31, hw = lane >> 5;
  const int hw8 = hw * 8;
  const int ig = i0 + l5;

  const float* f2b = f2 + b * 2048;
  const float f1v = f1[b * 2048 + ig];
  const float gm = gmax[b];
  const float mz = f1v + gm;
  const float m  = fmaxf(mz, 0.2f * mz);   // >= true masked row max (lrelu monotone)
  const float Az = f1v - m;
  const float Bz = 0.2f * f1v - m;

  // preload adj words for this lane's row & ks j-range (512 j = 16 words)
  unsigned awf[16];
  {
    const uint4* ap = reinterpret_cast<const uint4*>(adjm + (size_t)ig * 64 + ks * 16);
#pragma unroll
    for (int q = 0; q < 4; ++q) {
      uint4 v = ap[q];
      awf[4 * q] = v.x; awf[4 * q + 1] = v.y; awf[4 * q + 2] = v.z; awf[4 * q + 3] = v.w;
    }
  }

  const char* wbase = (const char*)whp +
      ((((size_t)b * 12 + ch * 3) * 128 + ks * 32) << 10) + lane * 16;

  const f32x16 zero16 = {0.f,0.f,0.f,0.f,0.f,0.f,0.f,0.f,0.f,0.f,0.f,0.f,0.f,0.f,0.f,0.f};
  f32x16 acc[3];
#pragma unroll
  for (int t = 0; t < 3; ++t) acc[t] = zero16;
  float denom = 0.f;

  short8 bfr[3][3];
  float4 ff[3][2];

#define LOADB(S, KK)                                                                    \
  { _Pragma("unroll")                                                                   \
    for (int tt = 0; tt < 3; ++tt)                                                      \
      bfr[S][tt] = *reinterpret_cast<const short8*>(wbase + (((size_t)tt * 128 + (KK)) << 10)); }
#define LOADF(S, KK)                                                                    \
  { const float* fp_ = f2b + ks * 512 + (KK) * 16 + hw8;                                \
    ff[S][0] = *(const float4*)fp_; ff[S][1] = *(const float4*)(fp_ + 4); }

#define PGEMM(S, KK)                                                                    \
  { const unsigned bits_ = (awf[(KK) >> 1] >> ((((KK) & 1) << 4) + hw8)) & 0xffu;       \
    const float gv[8] = {ff[S][0].x, ff[S][0].y, ff[S][0].z, ff[S][0].w,                \
                         ff[S][1].x, ff[S][1].y, ff[S][1].z, ff[S][1].w};               \
    union { unsigned u[4]; short8 s8; } cc;                                             \
    _Pragma("unroll")                                                                   \
    for (int pr = 0; pr < 4; ++pr) {                                                    \
      const int e = pr * 2;                                                             \
      float plo = ((bits_ >> e) & 1u)                                                   \
          ? __expf(fmaxf(Az + gv[e], fmaf(gv[e], 0.2f, Bz))) : 0.f;                     \
      float phi = ((bits_ >> (e + 1)) & 1u)                                             \
          ? __expf(fmaxf(Az + gv[e + 1], fmaf(gv[e + 1], 0.2f, Bz))) : 0.f;             \
      const unsigned ulo = __float_as_uint(plo) & 0xffff0000u;                          \
      const unsigned uhi = __float_as_uint(phi) & 0xffff0000u;                          \
      denom += __uint_as_float(ulo) + __uint_as_float(uhi);                             \
      cc.u[pr] = uhi | (ulo >> 16);                                                     \
    }                                                                                   \
    _Pragma("unroll")                                                                   \
    for (int qq = 0; qq < 3; ++qq)                                                      \
      acc[qq] = __builtin_amdgcn_mfma_f32_32x32x16_bf16(cc.s8, bfr[S][qq], acc[qq], 0, 0, 0); }

  LOADB(0, 0); LOADF(0, 0);
  LOADB(1, 1); LOADF(1, 1);
#pragma unroll
  for (int k = 0; k < 32; ++k) {
    const int s = k % 3;
    if (k < 30) {
      const int sn = (k + 2) % 3;
      LOADB(sn, k + 2); LOADF(sn, k + 2);
    }
    PGEMM(s, k);
  }
#undef LOADB
#undef LOADF
#undef PGEMM

  // ---- epilogue: combine 4 ks accumulators via LDS, normalize, elu, store ----
  float dn = denom + __shfl_xor(denom, 32);
  if (hw == 0) dred[ks * 32 + l5] = dn;
#pragma unroll
  for (int t = 0; t < 3; ++t) {
#pragma unroll
    for (int q = 0; q < 16; ++q) {
      const int row = (q & 3) + 8 * (q >> 2) + 4 * hw;
      red[ks][row][t * 32 + l5] = acc[t][q];
    }
  }
  __syncthreads();
  const size_t ob = ((size_t)b * 2048 + i0) * 384 + ch * 96;
#pragma unroll
  for (int p = 0; p < 12; ++p) {
    const int idx = p * 256 + tid;
    const int row = idx / 96;
    const int c = idx - row * 96;
    float v = red[0][row][c] + red[1][row][c] + red[2][row][c] + red[3][row][c];
    const float d = dred[row] + dred[32 + row] + dred[64 + row] + dred[96 + row];
    v /= d;
    v = v > 0.f ? v : expm1f(v);
    out[ob + (size_t)row * 384 + c] = v;
  }
}

extern "C" void kernel_launch(void* const* d_in, const int* in_sizes, int n_in,
                              void* d_out, int out_size, void* d_ws, size_t ws_size,
                              hipStream_t stream) {
  const float* x  = (const float*)d_in[0];
  const int* adj  = (const int*)d_in[1];
  const float* W  = (const float*)d_in[2];
  const float* a  = (const float*)d_in[3];
  const float* cw = (const float*)d_in[4];
  const float* cb = (const float*)d_in[5];
  float* out = (float*)d_out;

  char* ws = (char*)d_ws;
  unsigned short* xt  = (unsigned short*)ws; ws += (size_t)3145728 * 2;  // [8192][384] bf16
  unsigned short* Wt  = (unsigned short*)ws; ws += (size_t)147456 * 2;   // [384][384] bf16 (T)
  unsigned short* whp = (unsigned short*)ws; ws += (size_t)3145728 * 2;  // packed B-frags
  float* f1           = (float*)ws;          ws += (size_t)8192 * 4;
  float* f2           = (float*)ws;          ws += (size_t)8192 * 4;
  unsigned* adjm      = (unsigned*)ws;       ws += (size_t)2048 * 64 * 4;
  float* gmax         = (float*)ws;          ws += 64;

  conv_kernel<<<dim3(256, 4), 256, 0, stream>>>(x, cw, cb, xt);
  transpose_f2b_kernel<<<dim3(12, 12), 256, 0, stream>>>(W, Wt, 384, 384);
  adjmask_kernel<<<dim3(16384), 256, 0, stream>>>(adj, adjm);
  gemm_wh2_kernel<<<dim3(256), 512, 0, stream>>>(xt, Wt, a, whp, f1, f2);
  f2max_kernel<<<dim3(4), 256, 0, stream>>>(f2, gmax);
  attn6_kernel<<<dim3(1024), 256, 0, stream>>>(f1, f2, adjm, whp, gmax, out);
}

// Round 8
// 96.179 us; speedup vs baseline: 1.6626x; 1.6626x over previous
//
#include <hip/hip_runtime.h>

using short8 = __attribute__((ext_vector_type(8))) short;
using f32x4  = __attribute__((ext_vector_type(4))) float;
using f32x16 = __attribute__((ext_vector_type(16))) float;

__device__ __forceinline__ unsigned short f2bf(float f) {
  unsigned u = __float_as_uint(f);
  u += 0x7fffu + ((u >> 16) & 1u);
  return (unsigned short)(u >> 16);
}

// ---------------- Kernel A: temporal conv over flattened (N*F_IN) axis ----------------
__global__ __launch_bounds__(256) void conv_kernel(const float* __restrict__ x,
                                                   const float* __restrict__ cw,
                                                   const float* __restrict__ cb,
                                                   unsigned short* __restrict__ xt) {
  __shared__ float tile[12][264];
  __shared__ float cws[432];
  __shared__ float cbs[12];
  const int b  = blockIdx.y;
  const int p0 = blockIdx.x << 8;
  const int tid = threadIdx.x;
  for (int i = tid; i < 432; i += 256) cws[i] = cw[i];
  if (tid < 12) cbs[tid] = cb[tid];
  for (int t = 0; t < 12; ++t) {
    for (int i = tid; i < 258; i += 256) {
      int gp = p0 + i - 1;
      float v = 0.f;
      if (gp >= 0 && gp < 2048 * 32) {
        int n = gp >> 5, f = gp & 31;
        v = x[(((size_t)b * 2048 + n) * 12 + t) * 32 + f];
      }
      tile[t][i] = v;
    }
  }
  __syncthreads();
  float acc[12];
#pragma unroll
  for (int to = 0; to < 12; ++to) acc[to] = cbs[to];
#pragma unroll
  for (int ti = 0; ti < 12; ++ti) {
    float x0 = tile[ti][tid], x1 = tile[ti][tid + 1], x2 = tile[ti][tid + 2];
#pragma unroll
    for (int to = 0; to < 12; ++to) {
      const float* wp = &cws[(to * 12 + ti) * 3];
      acc[to] += x0 * wp[0] + x1 * wp[1] + x2 * wp[2];
    }
  }
  const int p = p0 + tid, n = p >> 5, f = p & 31;
  unsigned short* op = xt + ((size_t)b * 2048 + n) * 384 + f;
#pragma unroll
  for (int to = 0; to < 12; ++to) op[to * 32] = f2bf(acc[to]);
}

// ---------------- Transpose f32 [rows][cols] -> bf16 [cols][rows] (for W) ----------------
__global__ __launch_bounds__(256) void transpose_f2b_kernel(const float* __restrict__ in,
                                                            unsigned short* __restrict__ out,
                                                            int rows, int cols) {
  __shared__ float tile[32][33];
  const int r0 = blockIdx.x * 32, c0 = blockIdx.y * 32;
  const int li = threadIdx.x >> 5, ci = threadIdx.x & 31;
#pragma unroll
  for (int p = 0; p < 4; ++p) {
    int r = li + p * 8;
    tile[r][ci] = in[(size_t)(r0 + r) * cols + c0 + ci];
  }
  __syncthreads();
#pragma unroll
  for (int p = 0; p < 4; ++p) {
    int c = li + p * 8;
    out[(size_t)(c0 + c) * rows + r0 + ci] = f2bf(tile[ci][c]);
  }
}

// ---------------- adj int32 -> bitmask [2048][64] words ----------------
__global__ __launch_bounds__(256) void adjmask_kernel(const int* __restrict__ adj,
                                                      unsigned* __restrict__ adjm) {
  const int wv = (blockIdx.x << 2) + (threadIdx.x >> 6);
  const int lane = threadIdx.x & 63;
  const int row = wv >> 5, j0 = (wv & 31) << 6;
  unsigned long long mask = __ballot(adj[(size_t)row * 2048 + j0 + lane] > 0);
  if (lane == 0) {
    adjm[row * 64 + (j0 >> 5)]     = (unsigned)mask;
    adjm[row * 64 + (j0 >> 5) + 1] = (unsigned)(mask >> 32);
  }
}

// ---------------- Kernel B: Wh = xt @ W, writes PACKED B-frag tiles + fused f1/f2 ----------------
__global__ __launch_bounds__(512) void gemm_wh2_kernel(const unsigned short* __restrict__ xt,
                                                       const unsigned short* __restrict__ Wt,
                                                       const float* __restrict__ a,
                                                       unsigned short* __restrict__ whp,
                                                       float* __restrict__ f1,
                                                       float* __restrict__ f2) {
  __shared__ unsigned short wtile[32][392];
  __shared__ float s1s[32], s2s[32];
  const int tid = threadIdx.x;
  const int rb = blockIdx.x;
  const int b = rb >> 6, jg = rb & 63;
  const int r0 = rb << 5;
  const int w = tid >> 6, lane = tid & 63;
  const int rg = w >> 2, cg = w & 3;
  const int il = lane & 15, kg = lane >> 4;
  if (tid < 32) { s1s[tid] = 0.f; s2s[tid] = 0.f; }
  __syncthreads();

  f32x4 acc[6];
#pragma unroll
  for (int t = 0; t < 6; ++t) acc[t] = (f32x4){0.f, 0.f, 0.f, 0.f};
  const unsigned short* ap = xt + (size_t)(r0 + rg * 16 + il) * 384 + kg * 8;
#pragma unroll
  for (int kk = 0; kk < 12; ++kk) {
    short8 af = *reinterpret_cast<const short8*>(ap + kk * 32);
#pragma unroll
    for (int t = 0; t < 6; ++t) {
      const int c = cg * 96 + t * 16 + il;
      short8 bf = *reinterpret_cast<const short8*>(Wt + (size_t)c * 384 + kk * 32 + kg * 8);
      acc[t] = __builtin_amdgcn_mfma_f32_16x16x32_bf16(af, bf, acc[t], 0, 0, 0);
    }
  }
  float p1[4] = {0.f, 0.f, 0.f, 0.f}, p2[4] = {0.f, 0.f, 0.f, 0.f};
#pragma unroll
  for (int t = 0; t < 6; ++t) {
    const int c = cg * 96 + t * 16 + il;
    const float a1v = a[c], a2v = a[384 + c];
#pragma unroll
    for (int r = 0; r < 4; ++r) { p1[r] += acc[t][r] * a1v; p2[r] += acc[t][r] * a2v; }
  }
#pragma unroll
  for (int off = 1; off < 16; off <<= 1) {
#pragma unroll
    for (int r = 0; r < 4; ++r) { p1[r] += __shfl_xor(p1[r], off); p2[r] += __shfl_xor(p2[r], off); }
  }
  if (il == 0) {
#pragma unroll
    for (int r = 0; r < 4; ++r) {
      atomicAdd(&s1s[rg * 16 + kg * 4 + r], p1[r]);
      atomicAdd(&s2s[rg * 16 + kg * 4 + r], p2[r]);
    }
  }
#pragma unroll
  for (int t = 0; t < 6; ++t)
#pragma unroll
    for (int r = 0; r < 4; ++r)
      wtile[rg * 16 + kg * 4 + r][cg * 96 + t * 16 + il] = f2bf(acc[t][r]);
  __syncthreads();

#pragma unroll
  for (int rep = 0; rep < 3; ++rep) {
    const int flat = rep * 512 + tid;
    const int tile = flat >> 6, l = flat & 63;
    const int ct = tile >> 1, jh = tile & 1;
    const int l5 = l & 31, hw2 = l >> 5;
    short8 v;
#pragma unroll
    for (int e = 0; e < 8; ++e)
      v[e] = (short)wtile[jh * 16 + hw2 * 8 + e][ct * 32 + l5];
    *reinterpret_cast<short8*>((char*)whp +
        ((((size_t)b * 12 + ct) * 128 + jg * 2 + jh) << 10) + l * 16) = v;
  }
  if (tid < 32) { f1[r0 + tid] = s1s[tid]; f2[r0 + tid] = s2s[tid]; }
}

// ---------------- per-batch max of f2 ----------------
__global__ __launch_bounds__(256) void f2max_kernel(const float* __restrict__ f2,
                                                    float* __restrict__ gmax) {
  __shared__ float wm[4];
  const int b = blockIdx.x;
  const int tid = threadIdx.x;
  float m = -3.0e38f;
  for (int i = tid; i < 2048; i += 256) m = fmaxf(m, f2[b * 2048 + i]);
#pragma unroll
  for (int off = 32; off; off >>= 1) m = fmaxf(m, __shfl_xor(m, off));
  if ((tid & 63) == 0) wm[tid >> 6] = m;
  __syncthreads();
  if (tid == 0) gmax[b] = fmaxf(fmaxf(wm[0], wm[1]), fmaxf(wm[2], wm[3]));
}

// ---------------- Kernel E: attention v7 — NAMED-register 3-deep pipeline (no scratch) ----------------
// grid 1024: bi = rowgroup*16 + (b*4+ch); 4 waves = 4 ks (512 j each, 32 steps of 16 j).
// Wave: 32 rows x 96 cols (3 tiles, acc 48 regs). All pipeline state in named scalars
// (rule #20: no runtime-indexed register arrays). 3 blocks/CU target.
__global__ __launch_bounds__(256, 3) void attn7_kernel(const float* __restrict__ f1,
                                                       const float* __restrict__ f2,
                                                       const unsigned* __restrict__ adjm,
                                                       const unsigned short* __restrict__ whp,
                                                       const float* __restrict__ gmax,
                                                       float* __restrict__ out) {
  __shared__ float red[4][32][96];      // 48 KB
  __shared__ float dred[128];
  const int bi = blockIdx.x;
  const int c16 = bi & 15;
  const int b  = c16 >> 2;
  const int ch = c16 & 3;
  const int i0 = (bi >> 4) << 5;
  const int tid = threadIdx.x;
  const int ks = tid >> 6;
  const int lane = tid & 63;
  const int l5 = lane & 31, hw = lane >> 5;
  const int hw8 = hw * 8;
  const int ig = i0 + l5;

  const float* f2b = f2 + b * 2048;
  const unsigned* adjr = adjm + (size_t)ig * 64 + ks * 16;   // 16 words = this ks range
  const float f1v = f1[b * 2048 + ig];
  const float gm = gmax[b];
  const float mz = f1v + gm;
  const float m  = fmaxf(mz, 0.2f * mz);   // >= true masked row max (lrelu monotone)
  const float Az = f1v - m;
  const float Bz = 0.2f * f1v - m;

  const char* wbase = (const char*)whp +
      ((((size_t)b * 12 + ch * 3) * 128 + ks * 32) << 10) + lane * 16;

  const f32x16 zero16 = {0.f,0.f,0.f,0.f,0.f,0.f,0.f,0.f,0.f,0.f,0.f,0.f,0.f,0.f,0.f,0.f};
  f32x16 acc0 = zero16, acc1 = zero16, acc2 = zero16;
  float denom = 0.f;

  // named pipeline stages (A, B, C)
  short8 bA0, bA1, bA2, bB0, bB1, bB2, bC0, bC1, bC2;
  float4 fAa, fAb, fBa, fBb, fCa, fCb;
  unsigned wA, wB, wC;

#define LOADS(SUF, KK)                                                                  \
  {                                                                                     \
    const int kk_ = (KK) < 32 ? (KK) : 31;                                              \
    const char* bp_ = wbase + ((size_t)kk_ << 10);                                      \
    b##SUF##0 = *reinterpret_cast<const short8*>(bp_);                                  \
    b##SUF##1 = *reinterpret_cast<const short8*>(bp_ + (size_t)(128 << 10));            \
    b##SUF##2 = *reinterpret_cast<const short8*>(bp_ + (size_t)(256 << 10));            \
    const float* fp_ = f2b + ks * 512 + kk_ * 16 + hw8;                                 \
    f##SUF##a = *(const float4*)fp_;                                                    \
    f##SUF##b = *(const float4*)(fp_ + 4);                                              \
    w##SUF = adjr[kk_ >> 1];                                                            \
  }

#define BODY(SUF, KK)                                                                   \
  {                                                                                     \
    const unsigned bits_ = (w##SUF >> ((((KK) & 1) << 4) + hw8)) & 0xffu;               \
    const float gv[8] = {f##SUF##a.x, f##SUF##a.y, f##SUF##a.z, f##SUF##a.w,            \
                         f##SUF##b.x, f##SUF##b.y, f##SUF##b.z, f##SUF##b.w};           \
    union { unsigned u[4]; short8 s8; } cc;                                             \
    float ps_[8];                                                                       \
    _Pragma("unroll")                                                                   \
    for (int pr = 0; pr < 4; ++pr) {                                                    \
      const int e = pr * 2;                                                             \
      float plo = ((bits_ >> e) & 1u)                                                   \
          ? __expf(fmaxf(Az + gv[e], fmaf(gv[e], 0.2f, Bz))) : 0.f;                     \
      float phi = ((bits_ >> (e + 1)) & 1u)                                             \
          ? __expf(fmaxf(Az + gv[e + 1], fmaf(gv[e + 1], 0.2f, Bz))) : 0.f;             \
      const unsigned ulo = __float_as_uint(plo) & 0xffff0000u;                          \
      const unsigned uhi = __float_as_uint(phi) & 0xffff0000u;                          \
      ps_[e] = __uint_as_float(ulo); ps_[e + 1] = __uint_as_float(uhi);                 \
      cc.u[pr] = uhi | (ulo >> 16);                                                     \
    }                                                                                   \
    denom += ((ps_[0] + ps_[1]) + (ps_[2] + ps_[3])) +                                  \
             ((ps_[4] + ps_[5]) + (ps_[6] + ps_[7]));                                   \
    acc0 = __builtin_amdgcn_mfma_f32_32x32x16_bf16(cc.s8, b##SUF##0, acc0, 0, 0, 0);    \
    acc1 = __builtin_amdgcn_mfma_f32_32x32x16_bf16(cc.s8, b##SUF##1, acc1, 0, 0, 0);    \
    acc2 = __builtin_amdgcn_mfma_f32_32x32x16_bf16(cc.s8, b##SUF##2, acc2, 0, 0, 0);    \
  }

  LOADS(A, 0); LOADS(B, 1);
  for (int g = 0; g < 10; ++g) {
    const int k3 = 3 * g;
    LOADS(C, k3 + 2); BODY(A, k3);
    LOADS(A, k3 + 3); BODY(B, k3 + 1);
    LOADS(B, k3 + 4); BODY(C, k3 + 2);
  }
  BODY(A, 30); BODY(B, 31);
#undef LOADS
#undef BODY

  // ---- epilogue: combine 4 ks accumulators via LDS, normalize, elu, store ----
  float dn = denom + __shfl_xor(denom, 32);
  if (hw == 0) dred[ks * 32 + l5] = dn;

#define DUMP_ACC(ACCV, T)                                                               \
  _Pragma("unroll")                                                                     \
  for (int q = 0; q < 16; ++q) {                                                        \
    const int row = (q & 3) + 8 * (q >> 2) + 4 * hw;                                    \
    red[ks][row][(T) * 32 + l5] = ACCV[q];                                              \
  }
  DUMP_ACC(acc0, 0)
  DUMP_ACC(acc1, 1)
  DUMP_ACC(acc2, 2)
#undef DUMP_ACC

  __syncthreads();
  const size_t ob = ((size_t)b * 2048 + i0) * 384 + ch * 96;
#pragma unroll
  for (int p = 0; p < 12; ++p) {
    const int idx = p * 256 + tid;
    const int row = idx / 96;
    const int c = idx - row * 96;
    float v = red[0][row][c] + red[1][row][c] + red[2][row][c] + red[3][row][c];
    const float d = dred[row] + dred[32 + row] + dred[64 + row] + dred[96 + row];
    v /= d;
    v = v > 0.f ? v : expm1f(v);
    out[ob + (size_t)row * 384 + c] = v;
  }
}

extern "C" void kernel_launch(void* const* d_in, const int* in_sizes, int n_in,
                              void* d_out, int out_size, void* d_ws, size_t ws_size,
                              hipStream_t stream) {
  const float* x  = (const float*)d_in[0];
  const int* adj  = (const int*)d_in[1];
  const float* W  = (const float*)d_in[2];
  const float* a  = (const float*)d_in[3];
  const float* cw = (const float*)d_in[4];
  const float* cb = (const float*)d_in[5];
  float* out = (float*)d_out;

  char* ws = (char*)d_ws;
  unsigned short* xt  = (unsigned short*)ws; ws += (size_t)3145728 * 2;  // [8192][384] bf16
  unsigned short* Wt  = (unsigned short*)ws; ws += (size_t)147456 * 2;   // [384][384] bf16 (T)
  unsigned short* whp = (unsigned short*)ws; ws += (size_t)3145728 * 2;  // packed B-frags
  float* f1           = (float*)ws;          ws += (size_t)8192 * 4;
  float* f2           = (float*)ws;          ws += (size_t)8192 * 4;
  unsigned* adjm      = (unsigned*)ws;       ws += (size_t)2048 * 64 * 4;
  float* gmax         = (float*)ws;          ws += 64;

  conv_kernel<<<dim3(256, 4), 256, 0, stream>>>(x, cw, cb, xt);
  transpose_f2b_kernel<<<dim3(12, 12), 256, 0, stream>>>(W, Wt, 384, 384);
  adjmask_kernel<<<dim3(16384), 256, 0, stream>>>(adj, adjm);
  gemm_wh2_kernel<<<dim3(256), 512, 0, stream>>>(xt, Wt, a, whp, f1, f2);
  f2max_kernel<<<dim3(4), 256, 0, stream>>>(f2, gmax);
  attn7_kernel<<<dim3(1024), 256, 0, stream>>>(f1, f2, adjm, whp, gmax, out);
}

// Round 12
// 88.873 us; speedup vs baseline: 1.7993x; 1.0822x over previous
//
#include <hip/hip_runtime.h>

using short8 = __attribute__((ext_vector_type(8))) short;
using f32x4  = __attribute__((ext_vector_type(4))) float;
using f32x16 = __attribute__((ext_vector_type(16))) float;

__device__ __forceinline__ unsigned short f2bf(float f) {
  unsigned u = __float_as_uint(f);
  u += 0x7fffu + ((u >> 16) & 1u);
  return (unsigned short)(u >> 16);
}

// ---------------- Transpose f32 [rows][cols] -> bf16 [cols][rows] (for W) ----------------
__global__ __launch_bounds__(256) void transpose_f2b_kernel(const float* __restrict__ in,
                                                            unsigned short* __restrict__ out,
                                                            int rows, int cols) {
  __shared__ float tile[32][33];
  const int r0 = blockIdx.x * 32, c0 = blockIdx.y * 32;
  const int li = threadIdx.x >> 5, ci = threadIdx.x & 31;
#pragma unroll
  for (int p = 0; p < 4; ++p) {
    int r = li + p * 8;
    tile[r][ci] = in[(size_t)(r0 + r) * cols + c0 + ci];
  }
  __syncthreads();
#pragma unroll
  for (int p = 0; p < 4; ++p) {
    int c = li + p * 8;
    out[(size_t)(c0 + c) * rows + r0 + ci] = f2bf(tile[ci][c]);
  }
}

// ---------------- adj int32 -> bitmask [2048][64] words ----------------
__global__ __launch_bounds__(256) void adjmask_kernel(const int* __restrict__ adj,
                                                      unsigned* __restrict__ adjm) {
  const int wv = (blockIdx.x << 2) + (threadIdx.x >> 6);
  const int lane = threadIdx.x & 63;
  const int row = wv >> 5, j0 = (wv & 31) << 6;
  unsigned long long mask = __ballot(adj[(size_t)row * 2048 + j0 + lane] > 0);
  if (lane == 0) {
    adjm[row * 64 + (j0 >> 5)]     = (unsigned)mask;
    adjm[row * 64 + (j0 >> 5) + 1] = (unsigned)(mask >> 32);
  }
}

// ---------------- Kernel B: fused conv + Wh GEMM + pack + f1/f2 ----------------
// block: 32 gemm rows = (b, n in [jg*32, jg*32+32)); 512 thr = 8 waves (2 rg x 4 cg).
// whp[b][jc 128][ct 12][lane 64][8]: lane l elem e = Wh[b][jc*16 + (l>>5)*8 + e][ct*32 + (l&31)]
__global__ __launch_bounds__(512) void gemm_wh3_kernel(const float* __restrict__ x,
                                                       const float* __restrict__ cw,
                                                       const float* __restrict__ cb,
                                                       const unsigned short* __restrict__ Wt,
                                                       const float* __restrict__ a,
                                                       unsigned short* __restrict__ whp,
                                                       float* __restrict__ f1,
                                                       float* __restrict__ f2) {
  __shared__ __align__(16) char lds[49344 + 1792 + 256];
  float* xin = (float*)lds;                                   // [12][1028], 1026 used
  unsigned short* atile = (unsigned short*)lds;               // [32][392] (after conv)
  unsigned short* wtile = (unsigned short*)(lds + 25088);     // [32][392]
  float* cws = (float*)(lds + 49344);                         // 432
  float* cbs = cws + 448;                                     // 12
  float* s1s = (float*)(lds + 49344 + 1792);                  // 32
  float* s2s = s1s + 32;                                      // 32

  const int tid = threadIdx.x;
  const int rb = blockIdx.x;
  const int b = rb >> 6, jg = rb & 63;
  const int r0 = rb << 5;
  const int w = tid >> 6, lane = tid & 63;
  const int rg = w >> 2, cg = w & 3;
  const int il = lane & 15, kg = lane >> 4;

  // stage conv weights + x tile
  if (tid < 432) cws[tid] = cw[tid];
  if (tid < 12) cbs[tid] = cb[tid];
  if (tid < 32) { s1s[tid] = 0.f; s2s[tid] = 0.f; }
  const float* xb = x + (size_t)b * 2048 * 12 * 32;
#pragma unroll
  for (int t = 0; t < 12; ++t) {
    for (int i = tid; i < 1026; i += 512) {
      const int gp = jg * 1024 + i - 1;
      float v = 0.f;
      if ((unsigned)gp < 65536u) v = xb[((size_t)(gp >> 5) * 12 + t) * 32 + (gp & 31)];
      xin[t * 1028 + i] = v;
    }
  }
  __syncthreads();

  // conv: each thread 2 p's x 12 t_o
  const int ploc = tid * 2;
  float accv0[12], accv1[12];
#pragma unroll
  for (int to = 0; to < 12; ++to) { accv0[to] = cbs[to]; accv1[to] = cbs[to]; }
#pragma unroll
  for (int ti = 0; ti < 12; ++ti) {
    const float x0 = xin[ti * 1028 + ploc];
    const float x1 = xin[ti * 1028 + ploc + 1];
    const float x2 = xin[ti * 1028 + ploc + 2];
    const float x3 = xin[ti * 1028 + ploc + 3];
#pragma unroll
    for (int to = 0; to < 12; ++to) {
      const float* wp = &cws[(to * 12 + ti) * 3];
      const float w0 = wp[0], w1 = wp[1], w2 = wp[2];
      accv0[to] += x0 * w0 + x1 * w1 + x2 * w2;
      accv1[to] += x1 * w0 + x2 * w1 + x3 * w2;
    }
  }
  __syncthreads();   // all xin reads done before atile overwrite

  // write conv out as bf16 A-tile (atile overlaps xin space)
  {
    const int row = ploc >> 5, f = ploc & 31;
    unsigned* ap32 = (unsigned*)(atile + row * 392 + f);
#pragma unroll
    for (int to = 0; to < 12; ++to) {
      const unsigned lo = f2bf(accv0[to]), hi = f2bf(accv1[to]);
      ap32[to * 16] = lo | (hi << 16);     // 32 shorts = 16 u32 per t_o step
    }
  }
  __syncthreads();

  // MFMA: 32x384 = A(32x384) @ W(384x384), waves: rg rows-16, cg cols-96
  f32x4 acc[6];
#pragma unroll
  for (int t = 0; t < 6; ++t) acc[t] = (f32x4){0.f, 0.f, 0.f, 0.f};
  const unsigned short* arow = atile + (rg * 16 + il) * 392 + kg * 8;
#pragma unroll
  for (int kk = 0; kk < 12; ++kk) {
    short8 af = *reinterpret_cast<const short8*>(arow + kk * 32);
#pragma unroll
    for (int t = 0; t < 6; ++t) {
      const int c = cg * 96 + t * 16 + il;
      short8 bf = *reinterpret_cast<const short8*>(Wt + (size_t)c * 384 + kk * 32 + kg * 8);
      acc[t] = __builtin_amdgcn_mfma_f32_16x16x32_bf16(af, bf, acc[t], 0, 0, 0);
    }
  }
  // fused f1/f2
  float p1[4] = {0.f, 0.f, 0.f, 0.f}, p2[4] = {0.f, 0.f, 0.f, 0.f};
#pragma unroll
  for (int t = 0; t < 6; ++t) {
    const int c = cg * 96 + t * 16 + il;
    const float a1v = a[c], a2v = a[384 + c];
#pragma unroll
    for (int r = 0; r < 4; ++r) { p1[r] += acc[t][r] * a1v; p2[r] += acc[t][r] * a2v; }
  }
#pragma unroll
  for (int off = 1; off < 16; off <<= 1) {
#pragma unroll
    for (int r = 0; r < 4; ++r) { p1[r] += __shfl_xor(p1[r], off); p2[r] += __shfl_xor(p2[r], off); }
  }
  if (il == 0) {
#pragma unroll
    for (int r = 0; r < 4; ++r) {
      atomicAdd(&s1s[rg * 16 + kg * 4 + r], p1[r]);
      atomicAdd(&s2s[rg * 16 + kg * 4 + r], p2[r]);
    }
  }
#pragma unroll
  for (int t = 0; t < 6; ++t)
#pragma unroll
    for (int r = 0; r < 4; ++r)
      wtile[(rg * 16 + kg * 4 + r) * 392 + cg * 96 + t * 16 + il] = f2bf(acc[t][r]);
  __syncthreads();

  // pack B-frag tiles: 24 tiles (jh 2 x ct 12) x 64 lanes; layout [b][jc][ct]
#pragma unroll
  for (int rep = 0; rep < 3; ++rep) {
    const int flat = rep * 512 + tid;
    const int tile = flat >> 6, l = flat & 63;
    const int ct = tile >> 1, jh = tile & 1;
    const int l5 = l & 31, hw2 = l >> 5;
    short8 v;
#pragma unroll
    for (int e = 0; e < 8; ++e)
      v[e] = (short)wtile[(jh * 16 + hw2 * 8 + e) * 392 + ct * 32 + l5];
    *reinterpret_cast<short8*>((char*)whp +
        ((((size_t)b * 128 + jg * 2 + jh) * 12 + ct) << 10) + l * 16) = v;
  }
  if (tid < 32) { f1[r0 + tid] = s1s[tid]; f2[r0 + tid] = s2s[tid]; }
}

// ---------------- per-batch max of f2 + e2f2 table ----------------
__global__ __launch_bounds__(256) void f2max_kernel(const float* __restrict__ f2,
                                                    float* __restrict__ gmax,
                                                    float* __restrict__ e2f2) {
  __shared__ float wm[4];
  const int b = blockIdx.x;
  const int tid = threadIdx.x;
  float m = -3.0e38f;
  for (int i = tid; i < 2048; i += 256) {
    const float v = f2[b * 2048 + i];
    m = fmaxf(m, v);
    float2 w; w.x = __expf(v); w.y = __expf(0.2f * v);
    *reinterpret_cast<float2*>(e2f2 + (size_t)(b * 2048 + i) * 2) = w;
  }
#pragma unroll
  for (int off = 32; off; off >>= 1) m = fmaxf(m, __shfl_xor(m, off));
  if ((tid & 63) == 0) wm[tid >> 6] = m;
  __syncthreads();
  if (tid == 0) gmax[b] = fmaxf(fmaxf(wm[0], wm[1]), fmaxf(wm[2], wm[3]));
}

// ---------------- Kernel E: attention v8 ----------------
// grid 512: bi&1 = ch(192 cols), (bi&7)>>1 = b, bi>>3 = 32-row group. 4 waves = 4 ks.
// Wave: 32 rows x 192 cols, 32 steps x 16 j. Named depth-2 pipeline, adj preloaded,
// separable exp (no v_exp in loop). 2 waves/SIMD.
__global__ __launch_bounds__(256, 2) void attn8_kernel(const float* __restrict__ f1,
                                                       const float* __restrict__ e2f2,
                                                       const unsigned* __restrict__ adjm,
                                                       const unsigned short* __restrict__ whp,
                                                       const float* __restrict__ gmax,
                                                       float* __restrict__ out) {
  __shared__ float red[4][32][96];      // 48 KB
  __shared__ float dred[128];
  const int bi = blockIdx.x;
  const int ch = bi & 1;
  const int b  = (bi & 7) >> 1;
  const int i0 = (bi >> 3) << 5;
  const int tid = threadIdx.x;
  const int ks = tid >> 6;
  const int lane = tid & 63;
  const int l5 = lane & 31, hw = lane >> 5;
  const int hw8 = hw * 8;
  const int ig = i0 + l5;

  // adj preload: 16 words covering this lane's row, ks j-range, as named uint4s
  const uint4* ap_ = reinterpret_cast<const uint4*>(adjm + (size_t)ig * 64 + ks * 16);
  const uint4 aw0 = ap_[0], aw1 = ap_[1], aw2 = ap_[2], aw3 = ap_[3];

  // B-frag pointers: whp[b][jc][ct] layout; wave's jc = ks*32 + KK; ch picks ct 0-5/6-11
  const char* pA = (const char*)whp + ((((size_t)b * 128 + ks * 32) * 12) << 10) +
                   ch * 6144 + lane * 16;
  const char* pB = pA + 12288;
  const char* efbase = (const char*)e2f2 + (size_t)(b * 2048 + ks * 512 + hw8) * 8;

  const float f1v = f1[b * 2048 + ig];
  const float gm = gmax[b];
  const float mz = f1v + gm;
  const float m  = fmaxf(mz, 0.2f * mz);     // >= true masked row max
  const float E1 = __expf(f1v - m);
  const float F1 = __expf(0.2f * f1v - m);
  const float T  = __expf(-f1v);             // z>0  <=>  e2 > T

  const f32x16 zero16 = {0.f,0.f,0.f,0.f,0.f,0.f,0.f,0.f,0.f,0.f,0.f,0.f,0.f,0.f,0.f,0.f};
  f32x16 acc[6];
#pragma unroll
  for (int t = 0; t < 6; ++t) acc[t] = zero16;
  float denom = 0.f;

  short8 bA0, bA1, bA2, bA3, bA4, bA5, bB0, bB1, bB2, bB3, bB4, bB5;
  float4 efA0, efA1, efA2, efA3, efB0, efB1, efB2, efB3;

#define CAT3(X, Y, Z) X##Y##Z
#define EFV(S, N) CAT3(ef, S, N)
#define BFV(S, N) CAT3(b, S, N)

#define LOADB(S)                                                                        \
  { BFV(S,0) = *reinterpret_cast<const short8*>(p##S);                                  \
    BFV(S,1) = *reinterpret_cast<const short8*>(p##S + 1024);                           \
    BFV(S,2) = *reinterpret_cast<const short8*>(p##S + 2048);                           \
    BFV(S,3) = *reinterpret_cast<const short8*>(p##S + 3072);                           \
    const char* p4_ = p##S + 4096;                                                      \
    BFV(S,4) = *reinterpret_cast<const short8*>(p4_);                                   \
    BFV(S,5) = *reinterpret_cast<const short8*>(p4_ + 1024);                            \
    p##S += 24576; }

#define LOADEF(S, KK)                                                                   \
  { EFV(S,0) = *reinterpret_cast<const float4*>(efbase + (KK) * 128);                   \
    EFV(S,1) = *reinterpret_cast<const float4*>(efbase + (KK) * 128 + 16);              \
    EFV(S,2) = *reinterpret_cast<const float4*>(efbase + (KK) * 128 + 32);              \
    EFV(S,3) = *reinterpret_cast<const float4*>(efbase + (KK) * 128 + 48); }

#define PEL(EV, QV, BIT, DST)                                                           \
  { const bool pos_ = (EV) > T;                                                         \
    float jf_ = pos_ ? (EV) : (QV);                                                     \
    const float iv_ = pos_ ? E1 : F1;                                                   \
    jf_ = ((bits_ >> (BIT)) & 1u) ? jf_ : 0.f;                                          \
    DST = jf_ * iv_; }

#define PKBF(HI, LO) (((__float_as_uint(HI) + 0x8000u) & 0xffff0000u) |                 \
                      ((__float_as_uint(LO) + 0x8000u) >> 16))

#define STEP(S, W, SH, KK, DL)                                                          \
  { const unsigned bits_ = (W) >> ((SH) + hw8);                                         \
    float p0_, p1_, p2_, p3_, p4_, p5_, p6_, p7_;                                       \
    PEL(EFV(S,0).x, EFV(S,0).y, 0, p0_)  PEL(EFV(S,0).z, EFV(S,0).w, 1, p1_)            \
    PEL(EFV(S,1).x, EFV(S,1).y, 2, p2_)  PEL(EFV(S,1).z, EFV(S,1).w, 3, p3_)            \
    PEL(EFV(S,2).x, EFV(S,2).y, 4, p4_)  PEL(EFV(S,2).z, EFV(S,2).w, 5, p5_)            \
    PEL(EFV(S,3).x, EFV(S,3).y, 6, p6_)  PEL(EFV(S,3).z, EFV(S,3).w, 7, p7_)            \
    denom += (((p0_ + p1_) + (p2_ + p3_)) + ((p4_ + p5_) + (p6_ + p7_)));               \
    union { unsigned u[4]; short8 s8; } cc;                                             \
    cc.u[0] = PKBF(p1_, p0_); cc.u[1] = PKBF(p3_, p2_);                                 \
    cc.u[2] = PKBF(p5_, p4_); cc.u[3] = PKBF(p7_, p6_);                                 \
    acc[0] = __builtin_amdgcn_mfma_f32_32x32x16_bf16(cc.s8, BFV(S,0), acc[0], 0, 0, 0); \
    acc[1] = __builtin_amdgcn_mfma_f32_32x32x16_bf16(cc.s8, BFV(S,1), acc[1], 0, 0, 0); \
    acc[2] = __builtin_amdgcn_mfma_f32_32x32x16_bf16(cc.s8, BFV(S,2), acc[2], 0, 0, 0); \
    acc[3] = __builtin_amdgcn_mfma_f32_32x32x16_bf16(cc.s8, BFV(S,3), acc[3], 0, 0, 0); \
    acc[4] = __builtin_amdgcn_mfma_f32_32x32x16_bf16(cc.s8, BFV(S,4), acc[4], 0, 0, 0); \
    acc[5] = __builtin_amdgcn_mfma_f32_32x32x16_bf16(cc.s8, BFV(S,5), acc[5], 0, 0, 0); \
    if (DL) { LOADB(S) LOADEF(S, (KK) + 2) } }

#define GROUP(AW, K0)                                                                   \
  STEP(A, AW.x, 0, (K0) + 0, 1)  STEP(B, AW.x, 16, (K0) + 1, 1)                         \
  STEP(A, AW.y, 0, (K0) + 2, 1)  STEP(B, AW.y, 16, (K0) + 3, 1)                         \
  STEP(A, AW.z, 0, (K0) + 4, 1)  STEP(B, AW.z, 16, (K0) + 5, 1)                         \
  STEP(A, AW.w, 0, (K0) + 6, 1)  STEP(B, AW.w, 16, (K0) + 7, 1)

#define GROUPL(AW, K0)                                                                  \
  STEP(A, AW.x, 0, (K0) + 0, 1)  STEP(B, AW.x, 16, (K0) + 1, 1)                         \
  STEP(A, AW.y, 0, (K0) + 2, 1)  STEP(B, AW.y, 16, (K0) + 3, 1)                         \
  STEP(A, AW.z, 0, (K0) + 4, 1)  STEP(B, AW.z, 16, (K0) + 5, 1)                         \
  STEP(A, AW.w, 0, (K0) + 6, 0)  STEP(B, AW.w, 16, (K0) + 7, 0)

  // prologue: fill both stages
  LOADB(A) LOADB(B)
  LOADEF(A, 0) LOADEF(B, 1)

  GROUP(aw0, 0)
  GROUP(aw1, 8)
  GROUP(aw2, 16)
  GROUPL(aw3, 24)

#undef LOADB
#undef LOADEF
#undef PEL
#undef PKBF
#undef STEP
#undef GROUP
#undef GROUPL
#undef CAT3
#undef EFV
#undef BFV

  // ---- epilogue: combine 4 ks accumulators via LDS, normalize, elu, store ----
  float dn = denom + __shfl_xor(denom, 32);
  if (hw == 0) dred[ks * 32 + l5] = dn;

#pragma unroll
  for (int r = 0; r < 2; ++r) {
#pragma unroll
    for (int t3 = 0; t3 < 3; ++t3) {
      const int t = r * 3 + t3;
#pragma unroll
      for (int q = 0; q < 16; ++q) {
        const int row = (q & 3) + 8 * (q >> 2) + 4 * hw;
        red[ks][row][t3 * 32 + l5] = acc[t][q];
      }
    }
    __syncthreads();
    const size_t ob = ((size_t)b * 2048 + i0) * 384 + ch * 192 + r * 96;
#pragma unroll
    for (int p = 0; p < 12; ++p) {
      const int idx = p * 256 + tid;
      const int row = idx / 96;
      const int c = idx - row * 96;
      float v = red[0][row][c] + red[1][row][c] + red[2][row][c] + red[3][row][c];
      const float d = dred[row] + dred[32 + row] + dred[64 + row] + dred[96 + row];
      v /= d;
      v = v > 0.f ? v : expm1f(v);
      out[ob + (size_t)row * 384 + c] = v;
    }
    __syncthreads();
  }
}

extern "C" void kernel_launch(void* const* d_in, const int* in_sizes, int n_in,
                              void* d_out, int out_size, void* d_ws, size_t ws_size,
                              hipStream_t stream) {
  const float* x  = (const float*)d_in[0];
  const int* adj  = (const int*)d_in[1];
  const float* W  = (const float*)d_in[2];
  const float* a  = (const float*)d_in[3];
  const float* cw = (const float*)d_in[4];
  const float* cb = (const float*)d_in[5];
  float* out = (float*)d_out;

  char* ws = (char*)d_ws;
  unsigned short* Wt  = (unsigned short*)ws; ws += (size_t)147456 * 2;   // [384][384] bf16 (T)
  unsigned short* whp = (unsigned short*)ws; ws += (size_t)3145728 * 2;  // packed B-frags [b][jc][ct]
  float* f1           = (float*)ws;          ws += (size_t)8192 * 4;
  float* f2           = (float*)ws;          ws += (size_t)8192 * 4;
  unsigned* adjm      = (unsigned*)ws;       ws += (size_t)2048 * 64 * 4;
  float* gmax         = (float*)ws;          ws += 64;
  float* e2f2         = (float*)ws;          ws += (size_t)8192 * 2 * 4; // [b][j][2]

  transpose_f2b_kernel<<<dim3(12, 12), 256, 0, stream>>>(W, Wt, 384, 384);
  adjmask_kernel<<<dim3(16384), 256, 0, stream>>>(adj, adjm);
  gemm_wh3_kernel<<<dim3(256), 512, 0, stream>>>(x, cw, cb, Wt, a, whp, f1, f2);
  f2max_kernel<<<dim3(4), 256, 0, stream>>>(f2, gmax, e2f2);
  attn8_kernel<<<dim3(512), 256, 0, stream>>>(f1, e2f2, adjm, whp, gmax, out);
}